// Round 6
// baseline (152.338 us; speedup 1.0000x reference)
//
#include <hip/hip_runtime.h>
#include <hip/hip_fp16.h>

#define D 512
#define NTOK 512
#define BINS 64

typedef float v4f __attribute__((ext_vector_type(4)));
typedef int v4i __attribute__((ext_vector_type(4)));
typedef short short8 __attribute__((ext_vector_type(8)));
typedef _Float16 h8 __attribute__((ext_vector_type(8)));
typedef _Float16 h4 __attribute__((ext_vector_type(4)));
typedef _Float16 h2 __attribute__((ext_vector_type(2)));

__device__ __forceinline__ h2 sp2(float f) {
    _Float16 h = (_Float16)f;
    h2 v = {h, h};
    return v;
}

// Polynomial gelu, transcendental-free, all v_pk_*_f16 full-rate ops.
// Identity: gelu(x) = max(x,0) + gelu(-|x|)  (exact: gelu(x)-gelu(-x)=x).
// Negative side clamped to [-4,0] (|gelu(-4)|=1.3e-4, so clamp error <1.3e-4),
// gelu(xc) = xc/2 + z*Q(z), z=(xc/4)^2 in [0,1]; Q deg-7, coeffs about z=0.5
// computed on-device in double (see coeff block in k_proj).
__device__ __forceinline__ h2 gelu_pk(h2 x, const h2* C) {
    h2 xm = __builtin_elementwise_min(x, -x);            // -|x|
    h2 xc = __builtin_elementwise_max(xm, sp2(-4.0f));   // [-4, 0]
    h2 zq = xc * sp2(0.25f);                             // exact scale
    h2 z = zq * zq;                                      // [0, 1]
    h2 y = z - sp2(0.5f);
    h2 q = C[7];
    q = __builtin_elementwise_fma(q, y, C[6]);
    q = __builtin_elementwise_fma(q, y, C[5]);
    q = __builtin_elementwise_fma(q, y, C[4]);
    q = __builtin_elementwise_fma(q, y, C[3]);
    q = __builtin_elementwise_fma(q, y, C[2]);
    q = __builtin_elementwise_fma(q, y, C[1]);
    q = __builtin_elementwise_fma(q, y, C[0]);
    h2 t = z * q;                                        // E(xc) = gelu(xc)-xc/2
    h2 g = __builtin_elementwise_fma(xc, sp2(0.5f), t);  // gelu(xc) (xc<=0)
    h2 r = __builtin_elementwise_max(x, sp2(0.0f));
    return r + g;
}

__device__ __forceinline__ h2 bch2(int v) { return __builtin_bit_cast(h2, v); }

// Fused stage-1 projection (fp32 math, f16 output) + W2 f16 fragment pack
// + gelu polynomial coefficient computation (double precision, device erf).
// Blocks 0..511: proj. Blocks 512..527: pack W2. Block 528: coeffs.
__global__ __launch_bounds__(256) void k_proj(const float* __restrict__ x,
                                              const float* __restrict__ W1,
                                              const float* __restrict__ b1,
                                              const float* __restrict__ W2,
                                              __half* __restrict__ hi,
                                              __half* __restrict__ hj,
                                              short8* __restrict__ Bp,
                                              int* __restrict__ cw) {
    const int b = blockIdx.x;
    if (b == 528) {
        if (threadIdx.x == 0) {
            const double PI = 3.14159265358979323846;
            double zn[8], yn[8], c[8];
            for (int k = 0; k < 8; ++k) {
                zn[k] = 0.5 - 0.5 * cos(PI * (2 * k + 1) / 16.0);
                yn[k] = zn[k] - 0.5;
                // Q(z) = 2*erf(sqrt(8z))/sqrt(z)  == E(x)/z with x=-4*sqrt(z)
                c[k] = 2.0 * erf(sqrt(8.0 * zn[k])) / sqrt(zn[k]);
            }
            // Newton divided differences (in-place)
            for (int j = 1; j < 8; ++j)
                for (int i = 7; i >= j; --i)
                    c[i] = (c[i] - c[i - 1]) / (zn[i] - zn[i - j]);
            // expand to monomial in y = z - 0.5
            double a[8] = {0, 0, 0, 0, 0, 0, 0, 0};
            a[0] = c[7];
            for (int i = 6; i >= 0; --i) {
                for (int j = 7; j >= 1; --j) a[j] = a[j - 1] - yn[i] * a[j];
                a[0] = c[i] - yn[i] * a[0];
            }
            for (int j = 0; j < 8; ++j) {
                _Float16 h = (_Float16)a[j];
                int us = (int)(unsigned short)__builtin_bit_cast(unsigned short, h);
                cw[j] = us | (us << 16);
            }
        }
        return;
    }
    if (b >= 512) {
        const int tid = (b - 512) * 256 + threadIdx.x;  // 0..4095
        const int ll = tid & 63;
        const int nt = (tid >> 6) & 3;
        const int kt = tid >> 8;
        const int colp = nt * 16 + (ll & 15);
        const int krow = kt * 32 + (ll >> 4) * 8;
        short8 v;
#pragma unroll
        for (int u = 0; u < 8; ++u) {
            _Float16 hv = (_Float16)W2[(size_t)(krow + u) * BINS + colp];  // RTE
            v[u] = __builtin_bit_cast(short, hv);
        }
        Bp[tid] = v;
        return;
    }
    const int rb = b >> 4, cg = b & 15;
    __shared__ __align__(16) float xs[16][516];  // +4 pad: conflict-free reads
    const float* xsrc = x + (size_t)rb * 16 * D;
#pragma unroll
    for (int i = 0; i < 8; ++i) {
        int e = (threadIdx.x + 256 * i) * 4;
        *(v4f*)&xs[e >> 9][e & 511] = *(const v4f*)(xsrc + e);
    }
    __syncthreads();

    const int l = threadIdx.x & 63;
    const int w = threadIdx.x >> 6;
    const int row = w * 4 + (l >> 4);       // 0..15
    const int col4 = (l & 15) * 4;
    const int half = cg >> 3;
    const int e0 = (cg & 7) * 64 + col4;
    const float* Wp = W1 + (size_t)half * (D * D) + e0;
    v4f acc = {0.f, 0.f, 0.f, 0.f};
    if (half == 0) acc = *(const v4f*)(b1 + e0);
#pragma unroll 4
    for (int k = 0; k < D; k += 4) {
        v4f xa = *(const v4f*)&xs[row][k];
        v4f w0 = *(const v4f*)(Wp + (size_t)(k + 0) * D);
        v4f w1 = *(const v4f*)(Wp + (size_t)(k + 1) * D);
        v4f w2 = *(const v4f*)(Wp + (size_t)(k + 2) * D);
        v4f w3 = *(const v4f*)(Wp + (size_t)(k + 3) * D);
        acc += xa.x * w0;
        acc += xa.y * w1;
        acc += xa.z * w2;
        acc += xa.w * w3;
    }
    h4 o;
    o[0] = (_Float16)acc.x; o[1] = (_Float16)acc.y;
    o[2] = (_Float16)acc.z; o[3] = (_Float16)acc.w;
    __half* dst = (half ? hj : hi) + (size_t)(rb * 16 + row) * D + e0;
    *(h4*)dst = o;
}

// Main fused kernel: grid 1024; tile 16i x 16j, 4 waves, 4 i-rows/wave.
// f16 hi/hj staged per 64-k chunk in LDS; polynomial gelu feeds f16 MFMA.
__global__ __launch_bounds__(256) void k_main(const __half* __restrict__ hi,
                                              const __half* __restrict__ hj,
                                              const v4i* __restrict__ Bp,
                                              const float* __restrict__ b2,
                                              const int* __restrict__ cw,
                                              float* __restrict__ out) {
    const int l = threadIdx.x & 63;
    const int w = threadIdx.x >> 6;
    const int c = l & 15;   // MFMA col: A m-index (j-offset) / B,D n-offset
    const int q = l >> 4;   // quad: k-group for A/B, row-group for D
    const int ib = (blockIdx.x >> 5) * 16;
    const int j0 = (blockIdx.x & 31) * 16;

    h2 C[8];
#pragma unroll
    for (int j = 0; j < 8; ++j) C[j] = __builtin_bit_cast(h2, cw[j]);

    __shared__ __align__(16) short hic[16][72];  // 72 f16 row stride (16B-aligned rows)
    __shared__ __align__(16) short hjc[16][72];

    const int t = threadIdx.x;
    const int lr = (t & 127) >> 3;      // 0..15
    const int lc = (t & 7) * 8;         // f16 col 0..56
    const __half* gsrc = (t < 128 ? hi + (size_t)(ib + lr) * D
                                  : hj + (size_t)(j0 + lr) * D) + lc;
    short* ldst = (t < 128 ? &hic[lr][lc] : &hjc[lr][lc]);

    v4f acc[4][4] = {};  // [p(i)][nt]
    v4i pf = *(const v4i*)gsrc;  // prefetch chunk 0 (16B = 8 f16)

    for (int chunk = 0; chunk < 8; ++chunk) {
        *(v4i*)ldst = pf;
        __syncthreads();
        if (chunk < 7) pf = *(const v4i*)(gsrc + (chunk + 1) * 64);
        const int kt4 = chunk * 8;
#pragma unroll
        for (int h = 0; h < 2; ++h) {
            const int ko = h * 32 + q * 8;
            v4i hjraw = *(const v4i*)&hjc[c][ko];
            h2 j0h = bch2(hjraw.x), j1h = bch2(hjraw.y);
            h2 j2h = bch2(hjraw.z), j3h = bch2(hjraw.w);
            v4i bfr[4];
#pragma unroll
            for (int nt = 0; nt < 4; ++nt)
                bfr[nt] = Bp[(kt4 + h * 4 + nt) * 64 + l];
#pragma unroll
            for (int p = 0; p < 4; ++p) {
                v4i ar = *(const v4i*)&hic[w * 4 + p][ko];
                h2 g0 = gelu_pk(bch2(ar.x) + j0h, C);
                h2 g1 = gelu_pk(bch2(ar.y) + j1h, C);
                h2 g2 = gelu_pk(bch2(ar.z) + j2h, C);
                h2 g3 = gelu_pk(bch2(ar.w) + j3h, C);
                v4i ai = {__builtin_bit_cast(int, g0), __builtin_bit_cast(int, g1),
                          __builtin_bit_cast(int, g2), __builtin_bit_cast(int, g3)};
                h8 af = __builtin_bit_cast(h8, ai);
#pragma unroll
                for (int nt = 0; nt < 4; ++nt)
                    acc[p][nt] = __builtin_amdgcn_mfma_f32_16x16x32_f16(
                        af, __builtin_bit_cast(h8, bfr[nt]), acc[p][nt], 0, 0, 0);
            }
        }
        __syncthreads();
    }

    const int i0 = ib + w * 4;
#pragma unroll
    for (int p = 0; p < 4; ++p) {
        const size_t rowbase = ((size_t)(i0 + p) * NTOK + j0 + q * 4) * BINS;
#pragma unroll
        for (int nt = 0; nt < 4; ++nt) {
            const float bb = b2[nt * 16 + c];
            float* op = out + rowbase + nt * 16 + c;
#pragma unroll
            for (int rr = 0; rr < 4; ++rr)
                op[(size_t)rr * BINS] = acc[p][nt][rr] + bb;
        }
    }
}

extern "C" void kernel_launch(void* const* d_in, const int* in_sizes, int n_in,
                              void* d_out, int out_size, void* d_ws, size_t ws_size,
                              hipStream_t stream) {
    const float* x  = (const float*)d_in[0];
    const float* W1 = (const float*)d_in[1];
    const float* b1 = (const float*)d_in[2];
    const float* W2 = (const float*)d_in[3];
    const float* b2 = (const float*)d_in[4];
    float* out = (float*)d_out;

    char* ws = (char*)d_ws;
    __half* hi = (__half*)ws;                     // 512 KB
    __half* hj = (__half*)(ws + (512u << 10));    // 512 KB
    short8* Bp = (short8*)(ws + (1u << 20));      // 64 KB
    int* cw = (int*)(ws + (1u << 20) + (64u << 10));  // 32 B gelu poly coeffs

    k_proj<<<529, 256, 0, stream>>>(x, W1, b1, W2, hi, hj, Bp, cw);
    k_main<<<1024, 256, 0, stream>>>(hi, hj, (const v4i*)Bp, b2, cw, out);
}